// Round 1
// baseline (577.596 us; speedup 1.0000x reference)
//
#include <hip/hip_runtime.h>

// ---------------------------------------------------------------------------
// DoshaGAT: 3-layer GAT (4x64 concat -> BN/ELU -> 4x32 concat -> BN/ELU ->
// 1-head x3 -> log_softmax). N=50000, E=850000 (incl. self-loops).
//
// Strategy:
//  - Build CSR (edges grouped by dst) once per call; reused by all layers.
//  - alpha = exp(e)/sum(exp(e)) computed WITHOUT segment-max (e bounded, exp
//    safe in f32; mathematically identical to the reference's max-shifted
//    form) and WITHOUT storing alpha: out = (sum ex*h[src]) / (sum ex + 1e-16).
//  - Aggregation: one wave per dst node, lanes feature-parallel (float4/float2
//    per lane), accumulate in registers, no atomics. BN+ELU fused in epilogue.
//  - GEMMs: f32 LDS-tiled 64x64x32, 4x4 per thread (no fp32 MFMA on CDNA4).
// ---------------------------------------------------------------------------

#define WSZ 64

// ---------------- CSR build ----------------

__global__ __launch_bounds__(256) void hist_kernel(const int* __restrict__ dst, int E,
                                                   int* __restrict__ deg) {
  int e = blockIdx.x * 256 + threadIdx.x;
  if (e < E) atomicAdd(&deg[dst[e]], 1);
}

// per-block (1024 elements) sums
__global__ __launch_bounds__(256) void block_sums_kernel(const int* __restrict__ deg, int n,
                                                         int* __restrict__ bsum) {
  __shared__ int sh[256];
  int t = threadIdx.x;
  int base = blockIdx.x * 1024 + t * 4;
  int v = 0;
#pragma unroll
  for (int j = 0; j < 4; ++j) {
    int idx = base + j;
    if (idx < n) v += deg[idx];
  }
  sh[t] = v;
  __syncthreads();
  for (int off = 128; off >= 1; off >>= 1) {
    if (t < off) sh[t] += sh[t + off];
    __syncthreads();
  }
  if (t == 0) bsum[blockIdx.x] = sh[0];
}

__global__ void tiny_scan_kernel(int* bsum, int nb) {
  if (threadIdx.x == 0 && blockIdx.x == 0) {
    int run = 0;
    for (int i = 0; i < nb; ++i) {
      int v = bsum[i];
      bsum[i] = run;
      run += v;
    }
  }
}

__global__ __launch_bounds__(256) void scan_write_kernel(const int* __restrict__ deg, int n,
                                                         const int* __restrict__ bbase,
                                                         int* __restrict__ row_start,
                                                         int* __restrict__ cursor) {
  __shared__ int sh[256];
  int t = threadIdx.x;
  int base = blockIdx.x * 1024 + t * 4;
  int v[4];
  int s = 0;
#pragma unroll
  for (int j = 0; j < 4; ++j) {
    int idx = base + j;
    v[j] = (idx < n) ? deg[idx] : 0;
    s += v[j];
  }
  sh[t] = s;
  __syncthreads();
  for (int off = 1; off < 256; off <<= 1) {
    int x = (t >= off) ? sh[t - off] : 0;
    __syncthreads();
    sh[t] += x;
    __syncthreads();
  }
  int excl = sh[t] - s + bbase[blockIdx.x];
#pragma unroll
  for (int j = 0; j < 4; ++j) {
    int idx = base + j;
    if (idx < n) {
      row_start[idx] = excl;
      cursor[idx] = excl;
    }
    excl += v[j];
  }
  if (blockIdx.x == gridDim.x - 1 && t == 255) row_start[n] = excl;  // == E
}

__global__ __launch_bounds__(256) void scatter_kernel(const int* __restrict__ src,
                                                      const int* __restrict__ dst, int E,
                                                      int* __restrict__ cursor,
                                                      int* __restrict__ csr_src) {
  int e = blockIdx.x * 256 + threadIdx.x;
  if (e < E) {
    int d = dst[e];
    int p = atomicAdd(&cursor[d], 1);
    csr_src[p] = src[e];
  }
}

// ---------------- f32 tiled GEMM: C[M,N] = A[M,K] @ B[K,N] ----------------
// 64x64 tile, BK=32, 256 threads, 4x4 per thread. Requires N%64==0, K%32==0.

__global__ __launch_bounds__(256) void gemm_f32(const float* __restrict__ A,
                                                const float* __restrict__ Bm,
                                                float* __restrict__ C, int M, int N, int K) {
  __shared__ __align__(16) float As[32][68];  // transposed: As[k][m]
  __shared__ __align__(16) float Bs[32][68];  // Bs[k][n]
  const int t = threadIdx.x;
  const int bm = blockIdx.x * 64;
  const int bn = blockIdx.y * 64;
  const int tm = (t & 15) * 4;
  const int tn = (t >> 4) * 4;
  const int ar = t >> 3;        // 0..31
  const int ak = (t & 7) * 4;   // 0..28
  const int bk = t >> 4;        // 0..15
  const int bc = (t & 15) * 4;  // 0..60
  float acc[4][4] = {};
  for (int k0 = 0; k0 < K; k0 += 32) {
#pragma unroll
    for (int h = 0; h < 2; ++h) {
      int row = ar + h * 32;
      int grow = bm + row;
      float4 a = make_float4(0.f, 0.f, 0.f, 0.f);
      if (grow < M) a = *(const float4*)(A + (size_t)grow * K + k0 + ak);
      As[ak + 0][row] = a.x;
      As[ak + 1][row] = a.y;
      As[ak + 2][row] = a.z;
      As[ak + 3][row] = a.w;
    }
#pragma unroll
    for (int h = 0; h < 2; ++h) {
      int krow = bk + h * 16;
      float4 b = *(const float4*)(Bm + (size_t)(k0 + krow) * N + bn + bc);
      *(float4*)&Bs[krow][bc] = b;
    }
    __syncthreads();
#pragma unroll
    for (int k = 0; k < 32; ++k) {
      float4 a = *(const float4*)&As[k][tm];
      float4 b = *(const float4*)&Bs[k][tn];
      float av[4] = {a.x, a.y, a.z, a.w};
      float bv[4] = {b.x, b.y, b.z, b.w};
#pragma unroll
      for (int i = 0; i < 4; ++i)
#pragma unroll
        for (int j = 0; j < 4; ++j) acc[i][j] += av[i] * bv[j];
    }
    __syncthreads();
  }
#pragma unroll
  for (int i = 0; i < 4; ++i) {
    int grow = bm + tm + i;
    if (grow < M) *(float4*)(C + (size_t)grow * N + bn + tn) = *(const float4*)acc[i];
  }
}

// ---------------- attention coefficients: als/ald per (node, head) ----------
// One wave per node; lane covers D/64 channels; width-16 shuffle reduce per head.

template <int D, int H>
__global__ __launch_bounds__(256) void attn_coeff(const float* __restrict__ h,
                                                  const float* __restrict__ a_s,
                                                  const float* __restrict__ a_d,
                                                  float* __restrict__ als,
                                                  float* __restrict__ ald, int n_nodes) {
  constexpr int VPT = D / WSZ;
  __shared__ float sas[D], sad[D];
  for (int i = threadIdx.x; i < D; i += 256) {
    sas[i] = a_s[i];
    sad[i] = a_d[i];
  }
  __syncthreads();
  int wid = threadIdx.x >> 6, lane = threadIdx.x & 63;
  int n = blockIdx.x * 4 + wid;
  if (n >= n_nodes) return;
  int c = lane * VPT;
  const float* hp = h + (size_t)n * D + c;
  float v[VPT];
  if constexpr (VPT == 4) {
    float4 tv = *(const float4*)hp;
    v[0] = tv.x; v[1] = tv.y; v[2] = tv.z; v[3] = tv.w;
  } else {
    float2 tv = *(const float2*)hp;
    v[0] = tv.x; v[1] = tv.y;
  }
  float ps = 0.f, pd = 0.f;
#pragma unroll
  for (int j = 0; j < VPT; ++j) {
    ps += v[j] * sas[c + j];
    pd += v[j] * sad[c + j];
  }
#pragma unroll
  for (int off = 8; off >= 1; off >>= 1) {
    ps += __shfl_xor(ps, off, 16);
    pd += __shfl_xor(pd, off, 16);
  }
  if ((lane & 15) == 0) {
    int hd = lane >> 4;
    als[(size_t)n * H + hd] = ps;
    ald[(size_t)n * H + hd] = pd;
  }
}

// ---------------- GAT aggregation + bias + BN + ELU -------------------------
// One wave per dst node; lane feature-parallel. alpha normalizer folded to a
// single scalar divide per (dst, head) at the end.

template <int D, int H>
__global__ __launch_bounds__(256) void gat_aggregate(
    const float* __restrict__ h, const float* __restrict__ als, const float* __restrict__ ald,
    const int* __restrict__ row_start, const int* __restrict__ csr_src,
    const float* __restrict__ bias, const float* __restrict__ gamma,
    const float* __restrict__ beta, const float* __restrict__ bmean,
    const float* __restrict__ bvar, float* __restrict__ out, int n_nodes) {
  constexpr int VPT = D / WSZ;
  int wid = threadIdx.x >> 6, lane = threadIdx.x & 63;
  int n = blockIdx.x * 4 + wid;
  if (n >= n_nodes) return;
  int c = lane * VPT;
  int hd = lane >> 4;  // head = c/(D/H) == lane/16 for both D=256,H=4 and D=128,H=4
  float aldv = ald[(size_t)n * H + hd];
  int row = row_start[n], end = row_start[n + 1];
  float acc[VPT] = {};
  float ssum = 0.f;
  for (int i = row; i < end; ++i) {
    int s = csr_src[i];
    float e = als[(size_t)s * H + hd] + aldv;
    e = (e > 0.f) ? e : 0.2f * e;  // leaky_relu, slope 0.2
    float ex = __expf(e);
    ssum += ex;
    const float* hp = h + (size_t)s * D + c;
    if constexpr (VPT == 4) {
      float4 hv = *(const float4*)hp;
      acc[0] += ex * hv.x;
      acc[1] += ex * hv.y;
      acc[2] += ex * hv.z;
      acc[3] += ex * hv.w;
    } else {
      float2 hv = *(const float2*)hp;
      acc[0] += ex * hv.x;
      acc[1] += ex * hv.y;
    }
  }
  float inv = 1.f / (ssum + 1e-16f);
#pragma unroll
  for (int j = 0; j < VPT; ++j) {
    float o = acc[j] * inv + bias[c + j];
    o = (o - bmean[c + j]) * rsqrtf(bvar[c + j] + 1e-5f) * gamma[c + j] + beta[c + j];
    o = (o > 0.f) ? o : (__expf(o) - 1.f);  // ELU
    acc[j] = o;
  }
  float* op = out + (size_t)n * D + c;
  if constexpr (VPT == 4)
    *(float4*)op = make_float4(acc[0], acc[1], acc[2], acc[3]);
  else
    *(float2*)op = make_float2(acc[0], acc[1]);
}

// ---------------- layer 3 prep: h3 = o2 @ W3 (K=128, N=3), als3/ald3 --------
// One wave per node; lane covers 2 k's; full-wave shuffle reduce.
// Packs [h3_0, h3_1, h3_2, als3] into a float4 row for the aggregation gather.

__global__ __launch_bounds__(256) void l3_prep_kernel(const float* __restrict__ o2,
                                                      const float* __restrict__ W3,
                                                      const float* __restrict__ a3s,
                                                      const float* __restrict__ a3d,
                                                      float4* __restrict__ h3p,
                                                      float* __restrict__ ald3, int n_nodes) {
  __shared__ float w[384];
  __shared__ float sa[6];
  for (int i = threadIdx.x; i < 384; i += 256) w[i] = W3[i];
  if (threadIdx.x < 3) {
    sa[threadIdx.x] = a3s[threadIdx.x];
    sa[3 + threadIdx.x] = a3d[threadIdx.x];
  }
  __syncthreads();
  int wid = threadIdx.x >> 6, lane = threadIdx.x & 63;
  int n = blockIdx.x * 4 + wid;
  if (n >= n_nodes) return;
  float2 xv = *(const float2*)(o2 + (size_t)n * 128 + lane * 2);
  int k0 = lane * 2;
  float p0 = xv.x * w[k0 * 3 + 0] + xv.y * w[(k0 + 1) * 3 + 0];
  float p1 = xv.x * w[k0 * 3 + 1] + xv.y * w[(k0 + 1) * 3 + 1];
  float p2 = xv.x * w[k0 * 3 + 2] + xv.y * w[(k0 + 1) * 3 + 2];
#pragma unroll
  for (int off = 32; off >= 1; off >>= 1) {
    p0 += __shfl_xor(p0, off, 64);
    p1 += __shfl_xor(p1, off, 64);
    p2 += __shfl_xor(p2, off, 64);
  }
  if (lane == 0) {
    float als = p0 * sa[0] + p1 * sa[1] + p2 * sa[2];
    float ald = p0 * sa[3] + p1 * sa[4] + p2 * sa[5];
    h3p[n] = make_float4(p0, p1, p2, als);
    ald3[n] = ald;
  }
}

// ---------------- layer 3 aggregation + log_softmax -------------------------
// One wave per dst node; lanes edge-parallel; 4-value full-wave reduce.

__global__ __launch_bounds__(256) void l3_agg_kernel(const float4* __restrict__ h3p,
                                                     const float* __restrict__ ald3,
                                                     const int* __restrict__ row_start,
                                                     const int* __restrict__ csr_src,
                                                     const float* __restrict__ b3,
                                                     float* __restrict__ out, int n_nodes) {
  int wid = threadIdx.x >> 6, lane = threadIdx.x & 63;
  int n = blockIdx.x * 4 + wid;
  if (n >= n_nodes) return;
  float aldv = ald3[n];
  int row = row_start[n], end = row_start[n + 1];
  float a0 = 0.f, a1 = 0.f, a2 = 0.f, ss = 0.f;
  for (int i = row + lane; i < end; i += 64) {
    int s = csr_src[i];
    float4 hv = h3p[s];
    float e = hv.w + aldv;
    e = (e > 0.f) ? e : 0.2f * e;
    float ex = __expf(e);
    ss += ex;
    a0 += ex * hv.x;
    a1 += ex * hv.y;
    a2 += ex * hv.z;
  }
#pragma unroll
  for (int off = 32; off >= 1; off >>= 1) {
    a0 += __shfl_xor(a0, off, 64);
    a1 += __shfl_xor(a1, off, 64);
    a2 += __shfl_xor(a2, off, 64);
    ss += __shfl_xor(ss, off, 64);
  }
  if (lane == 0) {
    float inv = 1.f / (ss + 1e-16f);
    float o0 = a0 * inv + b3[0];
    float o1 = a1 * inv + b3[1];
    float o2 = a2 * inv + b3[2];
    float m = fmaxf(o0, fmaxf(o1, o2));
    float lse = m + logf(expf(o0 - m) + expf(o1 - m) + expf(o2 - m));
    out[n * 3 + 0] = o0 - lse;
    out[n * 3 + 1] = o1 - lse;
    out[n * 3 + 2] = o2 - lse;
  }
}

// ---------------------------------------------------------------------------

extern "C" void kernel_launch(void* const* d_in, const int* in_sizes, int n_in,
                              void* d_out, int out_size, void* d_ws, size_t ws_size,
                              hipStream_t stream) {
  const float* x   = (const float*)d_in[0];
  const int*   ei  = (const int*)d_in[1];
  const float* W1  = (const float*)d_in[2];
  const float* a1s = (const float*)d_in[3];
  const float* a1d = (const float*)d_in[4];
  const float* b1  = (const float*)d_in[5];
  const float* g1v = (const float*)d_in[6];
  const float* be1 = (const float*)d_in[7];
  const float* m1  = (const float*)d_in[8];
  const float* v1  = (const float*)d_in[9];
  const float* W2  = (const float*)d_in[10];
  const float* a2s = (const float*)d_in[11];
  const float* a2d = (const float*)d_in[12];
  const float* b2  = (const float*)d_in[13];
  const float* g2v = (const float*)d_in[14];
  const float* be2 = (const float*)d_in[15];
  const float* m2  = (const float*)d_in[16];
  const float* v2  = (const float*)d_in[17];
  const float* W3  = (const float*)d_in[18];
  const float* a3s = (const float*)d_in[19];
  const float* a3d = (const float*)d_in[20];
  const float* b3  = (const float*)d_in[21];
  float* out = (float*)d_out;

  const int N = in_sizes[0] / 128;  // 50000
  const int E = in_sizes[1] / 2;    // 850000
  const int* srcv = ei;
  const int* dstv = ei + E;

  // workspace carve-up (~110 MB)
  float* wsf  = (float*)d_ws;
  float* h1   = wsf;                        // N*256 (reused as h2: N*128)
  float* o1   = h1 + (size_t)N * 256;       // N*256 (reused as o2: N*128)
  float* als1 = o1 + (size_t)N * 256;       // N*4
  float* ald1 = als1 + (size_t)N * 4;       // N*4
  float* als2 = ald1 + (size_t)N * 4;       // N*4
  float* ald2 = als2 + (size_t)N * 4;       // N*4
  float* h3p  = ald2 + (size_t)N * 4;       // N*4 (float4 rows: h3|als3)
  float* ald3 = h3p + (size_t)N * 4;        // N
  int* deg       = (int*)(ald3 + N);        // N
  int* row_start = deg + N;                 // N+1
  int* cursor    = row_start + (N + 1);     // N+1
  int* csr_src   = cursor + (N + 1);        // E
  int* bsum      = csr_src + E;             // ~64
  float* h2 = h1;
  float* o2 = o1;

  const int eb = (E + 255) / 256;
  const int nb = (N + 1023) / 1024;
  const int nodes4 = (N + 3) / 4;

  // CSR build (shared by all 3 layers)
  hipMemsetAsync(deg, 0, (size_t)N * sizeof(int), stream);
  hist_kernel<<<eb, 256, 0, stream>>>(dstv, E, deg);
  block_sums_kernel<<<nb, 256, 0, stream>>>(deg, N, bsum);
  tiny_scan_kernel<<<1, 64, 0, stream>>>(bsum, nb);
  scan_write_kernel<<<nb, 256, 0, stream>>>(deg, N, bsum, row_start, cursor);
  scatter_kernel<<<eb, 256, 0, stream>>>(srcv, dstv, E, cursor, csr_src);

  // layer 1
  dim3 grid1((N + 63) / 64, 4);
  gemm_f32<<<grid1, 256, 0, stream>>>(x, W1, h1, N, 256, 128);
  attn_coeff<256, 4><<<nodes4, 256, 0, stream>>>(h1, a1s, a1d, als1, ald1, N);
  gat_aggregate<256, 4><<<nodes4, 256, 0, stream>>>(h1, als1, ald1, row_start, csr_src,
                                                    b1, g1v, be1, m1, v1, o1, N);
  // layer 2
  dim3 grid2((N + 63) / 64, 2);
  gemm_f32<<<grid2, 256, 0, stream>>>(o1, W2, h2, N, 128, 256);
  attn_coeff<128, 4><<<nodes4, 256, 0, stream>>>(h2, a2s, a2d, als2, ald2, N);
  gat_aggregate<128, 4><<<nodes4, 256, 0, stream>>>(h2, als2, ald2, row_start, csr_src,
                                                    b2, g2v, be2, m2, v2, o2, N);
  // layer 3 + log_softmax
  l3_prep_kernel<<<nodes4, 256, 0, stream>>>(o2, W3, a3s, a3d, (float4*)h3p, ald3, N);
  l3_agg_kernel<<<nodes4, 256, 0, stream>>>((const float4*)h3p, ald3, row_start, csr_src,
                                            b3, out, N);
}

// Round 2
// 483.358 us; speedup vs baseline: 1.1950x; 1.1950x over previous
//
#include <hip/hip_runtime.h>

// ---------------------------------------------------------------------------
// DoshaGAT: 3-layer GAT (4x64 concat -> BN/ELU -> 4x32 concat -> BN/ELU ->
// 1-head x3 -> log_softmax). N=50000, E=850000 (incl. self-loops).
//
// R2: edge-gather rows stored as bf16 (RNE) -> halves random-gather traffic
//     (the #1 dispatch, 134us, FETCH 430MB). 4-edge software pipeline in the
//     aggregation loop to cover dependent-load latency. Accumulation f32.
// ---------------------------------------------------------------------------

#define WSZ 64

__device__ inline unsigned short f2bf(float f) {  // RNE f32->bf16
  unsigned u = __float_as_uint(f);
  u += 0x7FFFu + ((u >> 16) & 1u);
  return (unsigned short)(u >> 16);
}
__device__ inline float bf2f(unsigned short u) {
  return __uint_as_float(((unsigned)u) << 16);
}

// ---------------- CSR build ----------------

__global__ __launch_bounds__(256) void hist_kernel(const int* __restrict__ dst, int E,
                                                   int* __restrict__ deg) {
  int e = blockIdx.x * 256 + threadIdx.x;
  if (e < E) atomicAdd(&deg[dst[e]], 1);
}

__global__ __launch_bounds__(256) void block_sums_kernel(const int* __restrict__ deg, int n,
                                                         int* __restrict__ bsum) {
  __shared__ int sh[256];
  int t = threadIdx.x;
  int base = blockIdx.x * 1024 + t * 4;
  int v = 0;
#pragma unroll
  for (int j = 0; j < 4; ++j) {
    int idx = base + j;
    if (idx < n) v += deg[idx];
  }
  sh[t] = v;
  __syncthreads();
  for (int off = 128; off >= 1; off >>= 1) {
    if (t < off) sh[t] += sh[t + off];
    __syncthreads();
  }
  if (t == 0) bsum[blockIdx.x] = sh[0];
}

__global__ void tiny_scan_kernel(int* bsum, int nb) {
  if (threadIdx.x == 0 && blockIdx.x == 0) {
    int run = 0;
    for (int i = 0; i < nb; ++i) {
      int v = bsum[i];
      bsum[i] = run;
      run += v;
    }
  }
}

__global__ __launch_bounds__(256) void scan_write_kernel(const int* __restrict__ deg, int n,
                                                         const int* __restrict__ bbase,
                                                         int* __restrict__ row_start,
                                                         int* __restrict__ cursor) {
  __shared__ int sh[256];
  int t = threadIdx.x;
  int base = blockIdx.x * 1024 + t * 4;
  int v[4];
  int s = 0;
#pragma unroll
  for (int j = 0; j < 4; ++j) {
    int idx = base + j;
    v[j] = (idx < n) ? deg[idx] : 0;
    s += v[j];
  }
  sh[t] = s;
  __syncthreads();
  for (int off = 1; off < 256; off <<= 1) {
    int x = (t >= off) ? sh[t - off] : 0;
    __syncthreads();
    sh[t] += x;
    __syncthreads();
  }
  int excl = sh[t] - s + bbase[blockIdx.x];
#pragma unroll
  for (int j = 0; j < 4; ++j) {
    int idx = base + j;
    if (idx < n) {
      row_start[idx] = excl;
      cursor[idx] = excl;
    }
    excl += v[j];
  }
  if (blockIdx.x == gridDim.x - 1 && t == 255) row_start[n] = excl;  // == E
}

__global__ __launch_bounds__(256) void scatter_kernel(const int* __restrict__ src,
                                                      const int* __restrict__ dst, int E,
                                                      int* __restrict__ cursor,
                                                      int* __restrict__ csr_src) {
  int e = blockIdx.x * 256 + threadIdx.x;
  if (e < E) {
    int d = dst[e];
    int p = atomicAdd(&cursor[d], 1);
    csr_src[p] = src[e];
  }
}

// ---------------- f32 tiled GEMM: C[M,N] = A[M,K] @ B[K,N] ----------------

__global__ __launch_bounds__(256) void gemm_f32(const float* __restrict__ A,
                                                const float* __restrict__ Bm,
                                                float* __restrict__ C, int M, int N, int K) {
  __shared__ __align__(16) float As[32][68];  // transposed: As[k][m]
  __shared__ __align__(16) float Bs[32][68];  // Bs[k][n]
  const int t = threadIdx.x;
  const int bm = blockIdx.x * 64;
  const int bn = blockIdx.y * 64;
  const int tm = (t & 15) * 4;
  const int tn = (t >> 4) * 4;
  const int ar = t >> 3;        // 0..31
  const int ak = (t & 7) * 4;   // 0..28
  const int bk = t >> 4;        // 0..15
  const int bc = (t & 15) * 4;  // 0..60
  float acc[4][4] = {};
  for (int k0 = 0; k0 < K; k0 += 32) {
#pragma unroll
    for (int h = 0; h < 2; ++h) {
      int row = ar + h * 32;
      int grow = bm + row;
      float4 a = make_float4(0.f, 0.f, 0.f, 0.f);
      if (grow < M) a = *(const float4*)(A + (size_t)grow * K + k0 + ak);
      As[ak + 0][row] = a.x;
      As[ak + 1][row] = a.y;
      As[ak + 2][row] = a.z;
      As[ak + 3][row] = a.w;
    }
#pragma unroll
    for (int h = 0; h < 2; ++h) {
      int krow = bk + h * 16;
      float4 b = *(const float4*)(Bm + (size_t)(k0 + krow) * N + bn + bc);
      *(float4*)&Bs[krow][bc] = b;
    }
    __syncthreads();
#pragma unroll
    for (int k = 0; k < 32; ++k) {
      float4 a = *(const float4*)&As[k][tm];
      float4 b = *(const float4*)&Bs[k][tn];
      float av[4] = {a.x, a.y, a.z, a.w};
      float bv[4] = {b.x, b.y, b.z, b.w};
#pragma unroll
      for (int i = 0; i < 4; ++i)
#pragma unroll
        for (int j = 0; j < 4; ++j) acc[i][j] += av[i] * bv[j];
    }
    __syncthreads();
  }
#pragma unroll
  for (int i = 0; i < 4; ++i) {
    int grow = bm + tm + i;
    if (grow < M) *(float4*)(C + (size_t)grow * N + bn + tn) = *(const float4*)acc[i];
  }
}

// ---------------- attention coefficients + bf16 row emission ----------------
// One wave per node; lane covers D/64 channels; width-16 shuffle reduce per head.
// Also writes the bf16 copy of h used by the gather (fused: h row already in regs).

template <int D, int H>
__global__ __launch_bounds__(256) void attn_coeff(const float* __restrict__ h,
                                                  const float* __restrict__ a_s,
                                                  const float* __restrict__ a_d,
                                                  float* __restrict__ als,
                                                  float* __restrict__ ald,
                                                  unsigned short* __restrict__ h_bf,
                                                  int n_nodes) {
  constexpr int VPT = D / WSZ;
  __shared__ float sas[D], sad[D];
  for (int i = threadIdx.x; i < D; i += 256) {
    sas[i] = a_s[i];
    sad[i] = a_d[i];
  }
  __syncthreads();
  int wid = threadIdx.x >> 6, lane = threadIdx.x & 63;
  int n = blockIdx.x * 4 + wid;
  if (n >= n_nodes) return;
  int c = lane * VPT;
  const float* hp = h + (size_t)n * D + c;
  float v[VPT];
  if constexpr (VPT == 4) {
    float4 tv = *(const float4*)hp;
    v[0] = tv.x; v[1] = tv.y; v[2] = tv.z; v[3] = tv.w;
  } else {
    float2 tv = *(const float2*)hp;
    v[0] = tv.x; v[1] = tv.y;
  }
  // bf16 copy for the aggregation gather
  if constexpr (VPT == 4) {
    ushort4 u;
    u.x = f2bf(v[0]); u.y = f2bf(v[1]); u.z = f2bf(v[2]); u.w = f2bf(v[3]);
    *(ushort4*)(h_bf + (size_t)n * D + c) = u;
  } else {
    ushort2 u;
    u.x = f2bf(v[0]); u.y = f2bf(v[1]);
    *(ushort2*)(h_bf + (size_t)n * D + c) = u;
  }
  float ps = 0.f, pd = 0.f;
#pragma unroll
  for (int j = 0; j < VPT; ++j) {
    ps += v[j] * sas[c + j];
    pd += v[j] * sad[c + j];
  }
#pragma unroll
  for (int off = 8; off >= 1; off >>= 1) {
    ps += __shfl_xor(ps, off, 16);
    pd += __shfl_xor(pd, off, 16);
  }
  if ((lane & 15) == 0) {
    int hd = lane >> 4;
    als[(size_t)n * H + hd] = ps;
    ald[(size_t)n * H + hd] = pd;
  }
}

// ---------------- GAT aggregation + bias + BN + ELU -------------------------
// One wave per dst node; lane feature-parallel; bf16 row gather (8B/4B per
// lane); 4-edge software pipeline; f32 accumulation; scalar normalize at end.

template <int D, int H>
__global__ __launch_bounds__(256) void gat_aggregate(
    const unsigned short* __restrict__ h_bf, const float* __restrict__ als,
    const float* __restrict__ ald, const int* __restrict__ row_start,
    const int* __restrict__ csr_src, const float* __restrict__ bias,
    const float* __restrict__ gamma, const float* __restrict__ beta,
    const float* __restrict__ bmean, const float* __restrict__ bvar,
    float* __restrict__ out, int n_nodes) {
  constexpr int VPT = D / WSZ;
  int wid = threadIdx.x >> 6, lane = threadIdx.x & 63;
  int n = blockIdx.x * 4 + wid;
  if (n >= n_nodes) return;
  int c = lane * VPT;
  int hd = lane >> 4;  // head = lane/16 for both D=256 and D=128 (H=4)
  float aldv = ald[(size_t)n * H + hd];
  int row = row_start[n], end = row_start[n + 1];
  float acc[VPT] = {};
  float ssum = 0.f;
  int i = row;
  // 4-edge pipelined main loop: all 4 index loads, then 4 als loads, then 4
  // row loads are issued before the dependent math (compiler schedules the
  // vmem clusters together -> 4+ outstanding gathers per wave).
  for (; i + 3 < end; i += 4) {
    int s0 = csr_src[i + 0], s1 = csr_src[i + 1];
    int s2 = csr_src[i + 2], s3 = csr_src[i + 3];
    float e0 = als[(size_t)s0 * H + hd] + aldv;
    float e1 = als[(size_t)s1 * H + hd] + aldv;
    float e2 = als[(size_t)s2 * H + hd] + aldv;
    float e3 = als[(size_t)s3 * H + hd] + aldv;
    if constexpr (VPT == 4) {
      ushort4 u0 = *(const ushort4*)(h_bf + (size_t)s0 * D + c);
      ushort4 u1 = *(const ushort4*)(h_bf + (size_t)s1 * D + c);
      ushort4 u2 = *(const ushort4*)(h_bf + (size_t)s2 * D + c);
      ushort4 u3 = *(const ushort4*)(h_bf + (size_t)s3 * D + c);
      e0 = (e0 > 0.f) ? e0 : 0.2f * e0;
      e1 = (e1 > 0.f) ? e1 : 0.2f * e1;
      e2 = (e2 > 0.f) ? e2 : 0.2f * e2;
      e3 = (e3 > 0.f) ? e3 : 0.2f * e3;
      float x0 = __expf(e0), x1 = __expf(e1), x2 = __expf(e2), x3 = __expf(e3);
      ssum += (x0 + x1) + (x2 + x3);
      acc[0] += x0 * bf2f(u0.x) + x1 * bf2f(u1.x) + x2 * bf2f(u2.x) + x3 * bf2f(u3.x);
      acc[1] += x0 * bf2f(u0.y) + x1 * bf2f(u1.y) + x2 * bf2f(u2.y) + x3 * bf2f(u3.y);
      acc[2] += x0 * bf2f(u0.z) + x1 * bf2f(u1.z) + x2 * bf2f(u2.z) + x3 * bf2f(u3.z);
      acc[3] += x0 * bf2f(u0.w) + x1 * bf2f(u1.w) + x2 * bf2f(u2.w) + x3 * bf2f(u3.w);
    } else {
      ushort2 u0 = *(const ushort2*)(h_bf + (size_t)s0 * D + c);
      ushort2 u1 = *(const ushort2*)(h_bf + (size_t)s1 * D + c);
      ushort2 u2 = *(const ushort2*)(h_bf + (size_t)s2 * D + c);
      ushort2 u3 = *(const ushort2*)(h_bf + (size_t)s3 * D + c);
      e0 = (e0 > 0.f) ? e0 : 0.2f * e0;
      e1 = (e1 > 0.f) ? e1 : 0.2f * e1;
      e2 = (e2 > 0.f) ? e2 : 0.2f * e2;
      e3 = (e3 > 0.f) ? e3 : 0.2f * e3;
      float x0 = __expf(e0), x1 = __expf(e1), x2 = __expf(e2), x3 = __expf(e3);
      ssum += (x0 + x1) + (x2 + x3);
      acc[0] += x0 * bf2f(u0.x) + x1 * bf2f(u1.x) + x2 * bf2f(u2.x) + x3 * bf2f(u3.x);
      acc[1] += x0 * bf2f(u0.y) + x1 * bf2f(u1.y) + x2 * bf2f(u2.y) + x3 * bf2f(u3.y);
    }
  }
  for (; i < end; ++i) {
    int s = csr_src[i];
    float e = als[(size_t)s * H + hd] + aldv;
    e = (e > 0.f) ? e : 0.2f * e;
    float ex = __expf(e);
    ssum += ex;
    const unsigned short* hp = h_bf + (size_t)s * D + c;
    if constexpr (VPT == 4) {
      ushort4 u = *(const ushort4*)hp;
      acc[0] += ex * bf2f(u.x);
      acc[1] += ex * bf2f(u.y);
      acc[2] += ex * bf2f(u.z);
      acc[3] += ex * bf2f(u.w);
    } else {
      ushort2 u = *(const ushort2*)hp;
      acc[0] += ex * bf2f(u.x);
      acc[1] += ex * bf2f(u.y);
    }
  }
  float inv = 1.f / (ssum + 1e-16f);
#pragma unroll
  for (int j = 0; j < VPT; ++j) {
    float o = acc[j] * inv + bias[c + j];
    o = (o - bmean[c + j]) * rsqrtf(bvar[c + j] + 1e-5f) * gamma[c + j] + beta[c + j];
    o = (o > 0.f) ? o : (__expf(o) - 1.f);  // ELU
    acc[j] = o;
  }
  float* op = out + (size_t)n * D + c;
  if constexpr (VPT == 4)
    *(float4*)op = make_float4(acc[0], acc[1], acc[2], acc[3]);
  else
    *(float2*)op = make_float2(acc[0], acc[1]);
}

// ---------------- layer 3 prep: h3 = o2 @ W3 (K=128, N=3), als3/ald3 --------

__global__ __launch_bounds__(256) void l3_prep_kernel(const float* __restrict__ o2,
                                                      const float* __restrict__ W3,
                                                      const float* __restrict__ a3s,
                                                      const float* __restrict__ a3d,
                                                      float4* __restrict__ h3p,
                                                      float* __restrict__ ald3, int n_nodes) {
  __shared__ float w[384];
  __shared__ float sa[6];
  for (int i = threadIdx.x; i < 384; i += 256) w[i] = W3[i];
  if (threadIdx.x < 3) {
    sa[threadIdx.x] = a3s[threadIdx.x];
    sa[3 + threadIdx.x] = a3d[threadIdx.x];
  }
  __syncthreads();
  int wid = threadIdx.x >> 6, lane = threadIdx.x & 63;
  int n = blockIdx.x * 4 + wid;
  if (n >= n_nodes) return;
  float2 xv = *(const float2*)(o2 + (size_t)n * 128 + lane * 2);
  int k0 = lane * 2;
  float p0 = xv.x * w[k0 * 3 + 0] + xv.y * w[(k0 + 1) * 3 + 0];
  float p1 = xv.x * w[k0 * 3 + 1] + xv.y * w[(k0 + 1) * 3 + 1];
  float p2 = xv.x * w[k0 * 3 + 2] + xv.y * w[(k0 + 1) * 3 + 2];
#pragma unroll
  for (int off = 32; off >= 1; off >>= 1) {
    p0 += __shfl_xor(p0, off, 64);
    p1 += __shfl_xor(p1, off, 64);
    p2 += __shfl_xor(p2, off, 64);
  }
  if (lane == 0) {
    float als = p0 * sa[0] + p1 * sa[1] + p2 * sa[2];
    float ald = p0 * sa[3] + p1 * sa[4] + p2 * sa[5];
    h3p[n] = make_float4(p0, p1, p2, als);
    ald3[n] = ald;
  }
}

// ---------------- layer 3 aggregation + log_softmax -------------------------

__global__ __launch_bounds__(256) void l3_agg_kernel(const float4* __restrict__ h3p,
                                                     const float* __restrict__ ald3,
                                                     const int* __restrict__ row_start,
                                                     const int* __restrict__ csr_src,
                                                     const float* __restrict__ b3,
                                                     float* __restrict__ out, int n_nodes) {
  int wid = threadIdx.x >> 6, lane = threadIdx.x & 63;
  int n = blockIdx.x * 4 + wid;
  if (n >= n_nodes) return;
  float aldv = ald3[n];
  int row = row_start[n], end = row_start[n + 1];
  float a0 = 0.f, a1 = 0.f, a2 = 0.f, ss = 0.f;
  for (int i = row + lane; i < end; i += 64) {
    int s = csr_src[i];
    float4 hv = h3p[s];
    float e = hv.w + aldv;
    e = (e > 0.f) ? e : 0.2f * e;
    float ex = __expf(e);
    ss += ex;
    a0 += ex * hv.x;
    a1 += ex * hv.y;
    a2 += ex * hv.z;
  }
#pragma unroll
  for (int off = 32; off >= 1; off >>= 1) {
    a0 += __shfl_xor(a0, off, 64);
    a1 += __shfl_xor(a1, off, 64);
    a2 += __shfl_xor(a2, off, 64);
    ss += __shfl_xor(ss, off, 64);
  }
  if (lane == 0) {
    float inv = 1.f / (ss + 1e-16f);
    float o0 = a0 * inv + b3[0];
    float o1 = a1 * inv + b3[1];
    float o2 = a2 * inv + b3[2];
    float m = fmaxf(o0, fmaxf(o1, o2));
    float lse = m + logf(expf(o0 - m) + expf(o1 - m) + expf(o2 - m));
    out[n * 3 + 0] = o0 - lse;
    out[n * 3 + 1] = o1 - lse;
    out[n * 3 + 2] = o2 - lse;
  }
}

// ---------------------------------------------------------------------------

extern "C" void kernel_launch(void* const* d_in, const int* in_sizes, int n_in,
                              void* d_out, int out_size, void* d_ws, size_t ws_size,
                              hipStream_t stream) {
  const float* x   = (const float*)d_in[0];
  const int*   ei  = (const int*)d_in[1];
  const float* W1  = (const float*)d_in[2];
  const float* a1s = (const float*)d_in[3];
  const float* a1d = (const float*)d_in[4];
  const float* b1  = (const float*)d_in[5];
  const float* g1v = (const float*)d_in[6];
  const float* be1 = (const float*)d_in[7];
  const float* m1  = (const float*)d_in[8];
  const float* v1  = (const float*)d_in[9];
  const float* W2  = (const float*)d_in[10];
  const float* a2s = (const float*)d_in[11];
  const float* a2d = (const float*)d_in[12];
  const float* b2  = (const float*)d_in[13];
  const float* g2v = (const float*)d_in[14];
  const float* be2 = (const float*)d_in[15];
  const float* m2  = (const float*)d_in[16];
  const float* v2  = (const float*)d_in[17];
  const float* W3  = (const float*)d_in[18];
  const float* a3s = (const float*)d_in[19];
  const float* a3d = (const float*)d_in[20];
  const float* b3  = (const float*)d_in[21];
  float* out = (float*)d_out;

  const int N = in_sizes[0] / 128;  // 50000
  const int E = in_sizes[1] / 2;    // 850000
  const int* srcv = ei;
  const int* dstv = ei + E;

  // workspace carve-up (~135 MB)
  float* wsf  = (float*)d_ws;
  float* h1   = wsf;                        // N*256 (reused as h2: N*128)
  float* o1   = h1 + (size_t)N * 256;       // N*256 (reused as o2: N*128)
  float* als1 = o1 + (size_t)N * 256;       // N*4
  float* ald1 = als1 + (size_t)N * 4;       // N*4
  float* als2 = ald1 + (size_t)N * 4;       // N*4
  float* ald2 = als2 + (size_t)N * 4;       // N*4
  float* h3p  = ald2 + (size_t)N * 4;       // N*4 (float4 rows: h3|als3)
  float* ald3 = h3p + (size_t)N * 4;        // N
  int* deg       = (int*)(ald3 + N);        // N
  int* row_start = deg + N;                 // N+1
  int* cursor    = row_start + (N + 1);     // N+1
  int* csr_src   = cursor + (N + 1);        // E
  int* bsum      = csr_src + E;             // ~64
  unsigned short* h_bf = (unsigned short*)(bsum + 1024);  // N*256 bf16 (shared L1/L2)
  float* h2 = h1;
  float* o2 = o1;

  const int eb = (E + 255) / 256;
  const int nb = (N + 1023) / 1024;
  const int nodes4 = (N + 3) / 4;

  // CSR build (shared by all 3 layers)
  hipMemsetAsync(deg, 0, (size_t)N * sizeof(int), stream);
  hist_kernel<<<eb, 256, 0, stream>>>(dstv, E, deg);
  block_sums_kernel<<<nb, 256, 0, stream>>>(deg, N, bsum);
  tiny_scan_kernel<<<1, 64, 0, stream>>>(bsum, nb);
  scan_write_kernel<<<nb, 256, 0, stream>>>(deg, N, bsum, row_start, cursor);
  scatter_kernel<<<eb, 256, 0, stream>>>(srcv, dstv, E, cursor, csr_src);

  // layer 1
  dim3 grid1((N + 63) / 64, 4);
  gemm_f32<<<grid1, 256, 0, stream>>>(x, W1, h1, N, 256, 128);
  attn_coeff<256, 4><<<nodes4, 256, 0, stream>>>(h1, a1s, a1d, als1, ald1, h_bf, N);
  gat_aggregate<256, 4><<<nodes4, 256, 0, stream>>>(h_bf, als1, ald1, row_start, csr_src,
                                                    b1, g1v, be1, m1, v1, o1, N);
  // layer 2
  dim3 grid2((N + 63) / 64, 2);
  gemm_f32<<<grid2, 256, 0, stream>>>(o1, W2, h2, N, 128, 256);
  attn_coeff<128, 4><<<nodes4, 256, 0, stream>>>(h2, a2s, a2d, als2, ald2, h_bf, N);
  gat_aggregate<128, 4><<<nodes4, 256, 0, stream>>>(h_bf, als2, ald2, row_start, csr_src,
                                                    b2, g2v, be2, m2, v2, o2, N);
  // layer 3 + log_softmax
  l3_prep_kernel<<<nodes4, 256, 0, stream>>>(o2, W3, a3s, a3d, (float4*)h3p, ald3, N);
  l3_agg_kernel<<<nodes4, 256, 0, stream>>>((const float4*)h3p, ald3, row_start, csr_src,
                                            b3, out, N);
}

// Round 3
// 414.198 us; speedup vs baseline: 1.3945x; 1.1670x over previous
//
#include <hip/hip_runtime.h>

// ---------------------------------------------------------------------------
// DoshaGAT: 3-layer GAT. R3: bf16 MFMA GEMMs (16x16x32) with fused
// attention-coefficient epilogue; attn_coeff kernels eliminated; h stored
// bf16-only in a head-block-permuted layout (phys p = c16*VPT + cf <->
// logical L = cf*16 + c16 within each head block) so the MFMA epilogue can
// emit coalesced ushort4 stores. All consumers re-index by the same fixed
// permutation (BN params / a-vectors / W2 rows / W3 row indices).
// ---------------------------------------------------------------------------

#define WSZ 64

typedef short short8 __attribute__((ext_vector_type(8)));
typedef short short4v __attribute__((ext_vector_type(4)));
typedef float float4v __attribute__((ext_vector_type(4)));

__device__ inline unsigned short f2bf(float f) {  // RNE f32->bf16
  unsigned u = __float_as_uint(f);
  u += 0x7FFFu + ((u >> 16) & 1u);
  return (unsigned short)(u >> 16);
}
__device__ inline float bf2f(unsigned short u) {
  return __uint_as_float(((unsigned)u) << 16);
}

// ---------------- CSR build ----------------

__global__ __launch_bounds__(256) void hist_kernel(const int* __restrict__ dst, int E,
                                                   int* __restrict__ deg) {
  int e = blockIdx.x * 256 + threadIdx.x;
  if (e < E) atomicAdd(&deg[dst[e]], 1);
}

__global__ __launch_bounds__(256) void block_sums_kernel(const int* __restrict__ deg, int n,
                                                         int* __restrict__ bsum) {
  __shared__ int sh[256];
  int t = threadIdx.x;
  int base = blockIdx.x * 1024 + t * 4;
  int v = 0;
#pragma unroll
  for (int j = 0; j < 4; ++j) {
    int idx = base + j;
    if (idx < n) v += deg[idx];
  }
  sh[t] = v;
  __syncthreads();
  for (int off = 128; off >= 1; off >>= 1) {
    if (t < off) sh[t] += sh[t + off];
    __syncthreads();
  }
  if (t == 0) bsum[blockIdx.x] = sh[0];
}

__global__ void tiny_scan_kernel(int* bsum, int nb) {
  if (threadIdx.x == 0 && blockIdx.x == 0) {
    int run = 0;
    for (int i = 0; i < nb; ++i) {
      int v = bsum[i];
      bsum[i] = run;
      run += v;
    }
  }
}

__global__ __launch_bounds__(256) void scan_write_kernel(const int* __restrict__ deg, int n,
                                                         const int* __restrict__ bbase,
                                                         int* __restrict__ row_start,
                                                         int* __restrict__ cursor) {
  __shared__ int sh[256];
  int t = threadIdx.x;
  int base = blockIdx.x * 1024 + t * 4;
  int v[4];
  int s = 0;
#pragma unroll
  for (int j = 0; j < 4; ++j) {
    int idx = base + j;
    v[j] = (idx < n) ? deg[idx] : 0;
    s += v[j];
  }
  sh[t] = s;
  __syncthreads();
  for (int off = 1; off < 256; off <<= 1) {
    int x = (t >= off) ? sh[t - off] : 0;
    __syncthreads();
    sh[t] += x;
    __syncthreads();
  }
  int excl = sh[t] - s + bbase[blockIdx.x];
#pragma unroll
  for (int j = 0; j < 4; ++j) {
    int idx = base + j;
    if (idx < n) {
      row_start[idx] = excl;
      cursor[idx] = excl;
    }
    excl += v[j];
  }
  if (blockIdx.x == gridDim.x - 1 && t == 255) row_start[n] = excl;  // == E
}

__global__ __launch_bounds__(256) void scatter_kernel(const int* __restrict__ src,
                                                      const int* __restrict__ dst, int E,
                                                      int* __restrict__ cursor,
                                                      int* __restrict__ csr_src) {
  int e = blockIdx.x * 256 + threadIdx.x;
  if (e < E) {
    int d = dst[e];
    int p = atomicAdd(&cursor[d], 1);
    csr_src[p] = src[e];
  }
}

// ---------------- dtype conversion ----------------

__global__ __launch_bounds__(256) void conv_bf16x4(const float* __restrict__ in,
                                                   unsigned short* __restrict__ out, int n4) {
  int i = blockIdx.x * 256 + threadIdx.x;
  if (i < n4) {
    float4 v = ((const float4*)in)[i];
    ushort4 u;
    u.x = f2bf(v.x); u.y = f2bf(v.y); u.z = f2bf(v.z); u.w = f2bf(v.w);
    ((ushort4*)out)[i] = u;
  }
}

// W1 [128][256] -> W1t [256][128] bf16 (plain transpose; gemm1 K is unpermuted)
__global__ __launch_bounds__(256) void conv_w1t_kernel(const float* __restrict__ W1,
                                                       unsigned short* __restrict__ W1t) {
  int idx = blockIdx.x * 256 + threadIdx.x;  // 32768
  int n = idx >> 7, k = idx & 127;
  W1t[idx] = f2bf(W1[k * 256 + n]);
}

// W2 [256][128] -> W2t [128][256] bf16 with K rows permuted to the PHYSICAL
// layer-1 output layout: W2t[n][p] = W2[L256(p)][n].
__global__ __launch_bounds__(256) void conv_w2t_kernel(const float* __restrict__ W2,
                                                       unsigned short* __restrict__ W2t) {
  int idx = blockIdx.x * 256 + threadIdx.x;  // 32768
  int n = idx >> 8, p = idx & 255;
  int kl = (p & ~63) | ((p & 3) << 4) | ((p >> 2) & 15);
  W2t[idx] = f2bf(W2[kl * 128 + n]);
}

// ---------------- bf16 MFMA GEMM + fused attn-coeff epilogue ----------------
// C[M,BN] = A[M,K] @ B[K,BN]. Block: 64 rows x BN cols, 256 threads, 4 waves.
// Wave w = head w covers cols [w*BN/4, ...). CF = BN/64 column-fragments/wave.
// Output hout is bf16, column-permuted within each head block:
//   phys p = w*(CF*16) + c16*CF + cf  <->  logical L = w*(CF*16) + cf*16 + c16
// Epilogue also computes als/ald (dot with a_s/a_d over the head's columns).

template <int K, int BN>
__global__ __launch_bounds__(256) void gemm_mfma(
    const unsigned short* __restrict__ A,   // [M][K] bf16
    const unsigned short* __restrict__ Bt,  // [BN][K] bf16 (pre-transposed)
    const float* __restrict__ a_s, const float* __restrict__ a_d,  // [BN] logical
    unsigned short* __restrict__ hout,      // [M][BN] bf16 physical layout
    float* __restrict__ als, float* __restrict__ ald,  // [M][4]
    int M) {
  constexpr int CF = BN / 64;  // col frags per wave (4 for BN=256, 2 for BN=128)
  constexpr int PAD = 36;      // 72B rows: conflict-free b64 frag reads
  __shared__ unsigned short As[64][PAD];
  __shared__ unsigned short Bs[BN][PAD];
  const int t = threadIdx.x;
  const int w = t >> 6;       // wave id == head
  const int lane = t & 63;
  const int c16 = lane & 15;
  const int q = lane >> 4;
  const int bm = blockIdx.x * 64;
  const int arow = t >> 2;       // 0..63
  const int akc = (t & 3) * 8;   // 0,8,16,24

  float4v acc[4][CF];
#pragma unroll
  for (int rf = 0; rf < 4; ++rf)
#pragma unroll
    for (int cf = 0; cf < CF; ++cf) acc[rf][cf] = float4v{0.f, 0.f, 0.f, 0.f};

  for (int k0 = 0; k0 < K; k0 += 32) {
    {  // stage A tile 64x32
      int gr = bm + arow;
      uint4 v = make_uint4(0u, 0u, 0u, 0u);
      if (gr < M) v = *(const uint4*)(A + (size_t)gr * K + k0 + akc);
      *(uint2*)&As[arow][akc] = make_uint2(v.x, v.y);
      *(uint2*)&As[arow][akc + 4] = make_uint2(v.z, v.w);
    }
#pragma unroll
    for (int h = 0; h < BN / 64; ++h) {  // stage B tile BNx32 (k-contiguous)
      int n = (t >> 2) + h * 64;
      uint4 v = *(const uint4*)(Bt + (size_t)n * K + k0 + akc);
      *(uint2*)&Bs[n][akc] = make_uint2(v.x, v.y);
      *(uint2*)&Bs[n][akc + 4] = make_uint2(v.z, v.w);
    }
    __syncthreads();
    short8 af[4], bfr[CF];
#pragma unroll
    for (int rf = 0; rf < 4; ++rf) {
      short4v lo = *(short4v*)&As[rf * 16 + c16][q * 8];
      short4v hi = *(short4v*)&As[rf * 16 + c16][q * 8 + 4];
      af[rf] = __builtin_shufflevector(lo, hi, 0, 1, 2, 3, 4, 5, 6, 7);
    }
#pragma unroll
    for (int cf = 0; cf < CF; ++cf) {
      int n = w * (CF * 16) + cf * 16 + c16;
      short4v lo = *(short4v*)&Bs[n][q * 8];
      short4v hi = *(short4v*)&Bs[n][q * 8 + 4];
      bfr[cf] = __builtin_shufflevector(lo, hi, 0, 1, 2, 3, 4, 5, 6, 7);
    }
#pragma unroll
    for (int rf = 0; rf < 4; ++rf)
#pragma unroll
      for (int cf = 0; cf < CF; ++cf)
        acc[rf][cf] =
            __builtin_amdgcn_mfma_f32_16x16x32_bf16(af[rf], bfr[cf], acc[rf][cf], 0, 0, 0);
    __syncthreads();
  }

  // epilogue: packed bf16 store + als/ald dot (+ width-16 reduce)
  float sasv[CF], sadv[CF];
#pragma unroll
  for (int cf = 0; cf < CF; ++cf) {
    int L = w * (CF * 16) + cf * 16 + c16;
    sasv[cf] = a_s[L];
    sadv[cf] = a_d[L];
  }
#pragma unroll
  for (int rf = 0; rf < 4; ++rf) {
#pragma unroll
    for (int r = 0; r < 4; ++r) {
      int n = bm + rf * 16 + q * 4 + r;
      float ps = 0.f, pd = 0.f;
      unsigned short us[CF];
#pragma unroll
      for (int cf = 0; cf < CF; ++cf) {
        float v = acc[rf][cf][r];
        us[cf] = f2bf(v);
        ps += v * sasv[cf];
        pd += v * sadv[cf];
      }
#pragma unroll
      for (int off = 1; off <= 8; off <<= 1) {
        ps += __shfl_xor(ps, off, 16);
        pd += __shfl_xor(pd, off, 16);
      }
      if (n < M) {
        if constexpr (CF == 4) {
          ushort4 u;
          u.x = us[0]; u.y = us[1]; u.z = us[2]; u.w = us[3];
          *(ushort4*)(hout + (size_t)n * BN + w * 64 + c16 * 4) = u;
        } else {
          ushort2 u;
          u.x = us[0]; u.y = us[1];
          *(ushort2*)(hout + (size_t)n * BN + w * 32 + c16 * 2) = u;
        }
        if (c16 == 0) {
          als[(size_t)n * 4 + w] = ps;
          ald[(size_t)n * 4 + w] = pd;
        }
      }
    }
  }
}

// ---------------- GAT aggregation + bias + BN + ELU -------------------------
// One wave per dst node; lane feature-parallel over PHYSICAL columns; bf16
// gather; 4-edge pipeline; f32 accumulation. BN params indexed by LOGICAL col
// L = (lane>>4)*(VPT*16) + cf*16 + (lane&15). Output: bf16 physical (OBF) for
// the next GEMM's A operand, or f32 physical for l3_prep.

template <int D, bool OBF>
__global__ __launch_bounds__(256) void gat_aggregate(
    const unsigned short* __restrict__ h_bf, const float* __restrict__ als,
    const float* __restrict__ ald, const int* __restrict__ row_start,
    const int* __restrict__ csr_src, const float* __restrict__ bias,
    const float* __restrict__ gamma, const float* __restrict__ beta,
    const float* __restrict__ bmean, const float* __restrict__ bvar,
    void* __restrict__ outp, int n_nodes) {
  constexpr int VPT = D / WSZ;
  constexpr int H = 4;
  int wid = threadIdx.x >> 6, lane = threadIdx.x & 63;
  int n = blockIdx.x * 4 + wid;
  if (n >= n_nodes) return;
  int c = lane * VPT;  // physical col base
  int hd = lane >> 4;  // head (valid in both physical and logical)
  float aldv = ald[(size_t)n * H + hd];
  int row = row_start[n], end = row_start[n + 1];
  float acc[VPT] = {};
  float ssum = 0.f;
  int i = row;
  for (; i + 3 < end; i += 4) {
    int s0 = csr_src[i + 0], s1 = csr_src[i + 1];
    int s2 = csr_src[i + 2], s3 = csr_src[i + 3];
    float e0 = als[(size_t)s0 * H + hd] + aldv;
    float e1 = als[(size_t)s1 * H + hd] + aldv;
    float e2 = als[(size_t)s2 * H + hd] + aldv;
    float e3 = als[(size_t)s3 * H + hd] + aldv;
    if constexpr (VPT == 4) {
      ushort4 u0 = *(const ushort4*)(h_bf + (size_t)s0 * D + c);
      ushort4 u1 = *(const ushort4*)(h_bf + (size_t)s1 * D + c);
      ushort4 u2 = *(const ushort4*)(h_bf + (size_t)s2 * D + c);
      ushort4 u3 = *(const ushort4*)(h_bf + (size_t)s3 * D + c);
      e0 = (e0 > 0.f) ? e0 : 0.2f * e0;
      e1 = (e1 > 0.f) ? e1 : 0.2f * e1;
      e2 = (e2 > 0.f) ? e2 : 0.2f * e2;
      e3 = (e3 > 0.f) ? e3 : 0.2f * e3;
      float x0 = __expf(e0), x1 = __expf(e1), x2 = __expf(e2), x3 = __expf(e3);
      ssum += (x0 + x1) + (x2 + x3);
      acc[0] += x0 * bf2f(u0.x) + x1 * bf2f(u1.x) + x2 * bf2f(u2.x) + x3 * bf2f(u3.x);
      acc[1] += x0 * bf2f(u0.y) + x1 * bf2f(u1.y) + x2 * bf2f(u2.y) + x3 * bf2f(u3.y);
      acc[2] += x0 * bf2f(u0.z) + x1 * bf2f(u1.z) + x2 * bf2f(u2.z) + x3 * bf2f(u3.z);
      acc[3] += x0 * bf2f(u0.w) + x1 * bf2f(u1.w) + x2 * bf2f(u2.w) + x3 * bf2f(u3.w);
    } else {
      ushort2 u0 = *(const ushort2*)(h_bf + (size_t)s0 * D + c);
      ushort2 u1 = *(const ushort2*)(h_bf + (size_t)s1 * D + c);
      ushort2 u2 = *(const ushort2*)(h_bf + (size_t)s2 * D + c);
      ushort2 u3 = *(const ushort2*)(h_bf + (size_t)s3 * D + c);
      e0 = (e0 > 0.f) ? e0 : 0.2f * e0;
      e1 = (e1 > 0.f) ? e1 : 0.2f * e1;
      e2 = (e2 > 0.f) ? e2 : 0.2f * e2;
      e3 = (e3 > 0.f) ? e3 : 0.2f * e3;
      float x0 = __expf(e0), x1 = __expf(e1), x2 = __expf(e2), x3 = __expf(e3);
      ssum += (x0 + x1) + (x2 + x3);
      acc[0] += x0 * bf2f(u0.x) + x1 * bf2f(u1.x) + x2 * bf2f(u2.x) + x3 * bf2f(u3.x);
      acc[1] += x0 * bf2f(u0.y) + x1 * bf2f(u1.y) + x2 * bf2f(u2.y) + x3 * bf2f(u3.y);
    }
  }
  for (; i < end; ++i) {
    int s = csr_src[i];
    float e = als[(size_t)s * H + hd] + aldv;
    e = (e > 0.f) ? e : 0.2f * e;
    float ex = __expf(e);
    ssum += ex;
    const unsigned short* hp = h_bf + (size_t)s * D + c;
    if constexpr (VPT == 4) {
      ushort4 u = *(const ushort4*)hp;
      acc[0] += ex * bf2f(u.x);
      acc[1] += ex * bf2f(u.y);
      acc[2] += ex * bf2f(u.z);
      acc[3] += ex * bf2f(u.w);
    } else {
      ushort2 u = *(const ushort2*)hp;
      acc[0] += ex * bf2f(u.x);
      acc[1] += ex * bf2f(u.y);
    }
  }
  float inv = 1.f / (ssum + 1e-16f);
#pragma unroll
  for (int j = 0; j < VPT; ++j) {
    int cl = hd * (VPT * 16) + j * 16 + (lane & 15);  // logical col
    float o = acc[j] * inv + bias[cl];
    o = (o - bmean[cl]) * rsqrtf(bvar[cl] + 1e-5f) * gamma[cl] + beta[cl];
    o = (o > 0.f) ? o : (__expf(o) - 1.f);  // ELU
    acc[j] = o;
  }
  if constexpr (OBF) {
    ushort4 u;
    u.x = f2bf(acc[0]); u.y = f2bf(acc[1]); u.z = f2bf(acc[2]); u.w = f2bf(acc[3]);
    *(ushort4*)((unsigned short*)outp + (size_t)n * D + c) = u;
  } else {
    *(float2*)((float*)outp + (size_t)n * D + c) = make_float2(acc[0], acc[1]);
  }
}

// ---------------- layer 3 prep: h3 = o2 @ W3 (K=128 logical), als3/ald3 -----
// o2 is in PHYSICAL D=128 layout; lane's float2 at phys p=lane*2 corresponds
// to logical k0=(lane>>4)*32+(lane&15) and k1=k0+16.

__global__ __launch_bounds__(256) void l3_prep_kernel(const float* __restrict__ o2,
                                                      const float* __restrict__ W3,
                                                      const float* __restrict__ a3s,
                                                      const float* __restrict__ a3d,
                                                      float4* __restrict__ h3p,
                                                      float* __restrict__ ald3, int n_nodes) {
  __shared__ float w[384];
  __shared__ float sa[6];
  for (int i = threadIdx.x; i < 384; i += 256) w[i] = W3[i];
  if (threadIdx.x < 3) {
    sa[threadIdx.x] = a3s[threadIdx.x];
    sa[3 + threadIdx.x] = a3d[threadIdx.x];
  }
  __syncthreads();
  int wid = threadIdx.x >> 6, lane = threadIdx.x & 63;
  int n = blockIdx.x * 4 + wid;
  if (n >= n_nodes) return;
  float2 xv = *(const float2*)(o2 + (size_t)n * 128 + lane * 2);
  int k0 = (lane >> 4) * 32 + (lane & 15);
  int k1 = k0 + 16;
  float p0 = xv.x * w[k0 * 3 + 0] + xv.y * w[k1 * 3 + 0];
  float p1 = xv.x * w[k0 * 3 + 1] + xv.y * w[k1 * 3 + 1];
  float p2 = xv.x * w[k0 * 3 + 2] + xv.y * w[k1 * 3 + 2];
#pragma unroll
  for (int off = 32; off >= 1; off >>= 1) {
    p0 += __shfl_xor(p0, off, 64);
    p1 += __shfl_xor(p1, off, 64);
    p2 += __shfl_xor(p2, off, 64);
  }
  if (lane == 0) {
    float als = p0 * sa[0] + p1 * sa[1] + p2 * sa[2];
    float ald = p0 * sa[3] + p1 * sa[4] + p2 * sa[5];
    h3p[n] = make_float4(p0, p1, p2, als);
    ald3[n] = ald;
  }
}

// ---------------- layer 3 aggregation + log_softmax -------------------------

__global__ __launch_bounds__(256) void l3_agg_kernel(const float4* __restrict__ h3p,
                                                     const float* __restrict__ ald3,
                                                     const int* __restrict__ row_start,
                                                     const int* __restrict__ csr_src,
                                                     const float* __restrict__ b3,
                                                     float* __restrict__ out, int n_nodes) {
  int wid = threadIdx.x >> 6, lane = threadIdx.x & 63;
  int n = blockIdx.x * 4 + wid;
  if (n >= n_nodes) return;
  float aldv = ald3[n];
  int row = row_start[n], end = row_start[n + 1];
  float a0 = 0.f, a1 = 0.f, a2 = 0.f, ss = 0.f;
  for (int i = row + lane; i < end; i += 64) {
    int s = csr_src[i];
    float4 hv = h3p[s];
    float e = hv.w + aldv;
    e = (e > 0.f) ? e : 0.2f * e;
    float ex = __expf(e);
    ss += ex;
    a0 += ex * hv.x;
    a1 += ex * hv.y;
    a2 += ex * hv.z;
  }
#pragma unroll
  for (int off = 32; off >= 1; off >>= 1) {
    a0 += __shfl_xor(a0, off, 64);
    a1 += __shfl_xor(a1, off, 64);
    a2 += __shfl_xor(a2, off, 64);
    ss += __shfl_xor(ss, off, 64);
  }
  if (lane == 0) {
    float inv = 1.f / (ss + 1e-16f);
    float o0 = a0 * inv + b3[0];
    float o1 = a1 * inv + b3[1];
    float o2 = a2 * inv + b3[2];
    float m = fmaxf(o0, fmaxf(o1, o2));
    float lse = m + logf(expf(o0 - m) + expf(o1 - m) + expf(o2 - m));
    out[n * 3 + 0] = o0 - lse;
    out[n * 3 + 1] = o1 - lse;
    out[n * 3 + 2] = o2 - lse;
  }
}

// ---------------------------------------------------------------------------

extern "C" void kernel_launch(void* const* d_in, const int* in_sizes, int n_in,
                              void* d_out, int out_size, void* d_ws, size_t ws_size,
                              hipStream_t stream) {
  const float* x   = (const float*)d_in[0];
  const int*   ei  = (const int*)d_in[1];
  const float* W1  = (const float*)d_in[2];
  const float* a1s = (const float*)d_in[3];
  const float* a1d = (const float*)d_in[4];
  const float* b1  = (const float*)d_in[5];
  const float* g1v = (const float*)d_in[6];
  const float* be1 = (const float*)d_in[7];
  const float* m1  = (const float*)d_in[8];
  const float* v1  = (const float*)d_in[9];
  const float* W2  = (const float*)d_in[10];
  const float* a2s = (const float*)d_in[11];
  const float* a2d = (const float*)d_in[12];
  const float* b2  = (const float*)d_in[13];
  const float* g2v = (const float*)d_in[14];
  const float* be2 = (const float*)d_in[15];
  const float* m2  = (const float*)d_in[16];
  const float* v2  = (const float*)d_in[17];
  const float* W3  = (const float*)d_in[18];
  const float* a3s = (const float*)d_in[19];
  const float* a3d = (const float*)d_in[20];
  const float* b3  = (const float*)d_in[21];
  float* out = (float*)d_out;

  const int N = in_sizes[0] / 128;  // 50000
  const int E = in_sizes[1] / 2;    // 850000
  const int* srcv = ei;
  const int* dstv = ei + E;

  // workspace carve-up (~111 MB)
  float* wsf  = (float*)d_ws;
  float* o2   = wsf;                    // N*128 f32 (physical layout)
  float* als1 = o2 + (size_t)N * 128;   // N*4
  float* ald1 = als1 + (size_t)N * 4;
  float* als2 = ald1 + (size_t)N * 4;
  float* ald2 = als2 + (size_t)N * 4;
  float* h3p  = ald2 + (size_t)N * 4;   // N*4 (float4 rows)
  float* ald3 = h3p + (size_t)N * 4;    // N
  unsigned short* x_bf  = (unsigned short*)(ald3 + N);   // N*128
  unsigned short* h_bf1 = x_bf + (size_t)N * 128;        // N*256
  unsigned short* o1_bf = h_bf1 + (size_t)N * 256;       // N*256
  unsigned short* h_bf2 = o1_bf + (size_t)N * 256;       // N*128
  unsigned short* W1t   = h_bf2 + (size_t)N * 128;       // 256*128
  unsigned short* W2t   = W1t + 256 * 128;               // 128*256
  int* deg       = (int*)(W2t + 128 * 256);  // N
  int* row_start = deg + N;                  // N+1
  int* cursor    = row_start + (N + 1);      // N+1
  int* csr_src   = cursor + (N + 1);         // E
  int* bsum      = csr_src + E;              // 1024

  const int eb = (E + 255) / 256;
  const int nb = (N + 1023) / 1024;
  const int nodes4 = (N + 3) / 4;
  const int mblocks = (N + 63) / 64;

  // conversions
  conv_bf16x4<<<(N * 128 / 4 + 255) / 256, 256, 0, stream>>>(x, x_bf, N * 128 / 4);
  conv_w1t_kernel<<<128, 256, 0, stream>>>(W1, W1t);
  conv_w2t_kernel<<<128, 256, 0, stream>>>(W2, W2t);

  // CSR build (shared by all 3 layers)
  hipMemsetAsync(deg, 0, (size_t)N * sizeof(int), stream);
  hist_kernel<<<eb, 256, 0, stream>>>(dstv, E, deg);
  block_sums_kernel<<<nb, 256, 0, stream>>>(deg, N, bsum);
  tiny_scan_kernel<<<1, 64, 0, stream>>>(bsum, nb);
  scan_write_kernel<<<nb, 256, 0, stream>>>(deg, N, bsum, row_start, cursor);
  scatter_kernel<<<eb, 256, 0, stream>>>(srcv, dstv, E, cursor, csr_src);

  // layer 1: h1 = x @ W1 (+ als1/ald1 fused), then aggregate -> o1_bf (bf16)
  gemm_mfma<128, 256><<<mblocks, 256, 0, stream>>>(x_bf, W1t, a1s, a1d, h_bf1, als1, ald1, N);
  gat_aggregate<256, true><<<nodes4, 256, 0, stream>>>(h_bf1, als1, ald1, row_start, csr_src,
                                                       b1, g1v, be1, m1, v1, o1_bf, N);
  // layer 2
  gemm_mfma<256, 128><<<mblocks, 256, 0, stream>>>(o1_bf, W2t, a2s, a2d, h_bf2, als2, ald2, N);
  gat_aggregate<128, false><<<nodes4, 256, 0, stream>>>(h_bf2, als2, ald2, row_start, csr_src,
                                                        b2, g2v, be2, m2, v2, o2, N);
  // layer 3 + log_softmax
  l3_prep_kernel<<<nodes4, 256, 0, stream>>>(o2, W3, a3s, a3d, (float4*)h3p, ald3, N);
  l3_agg_kernel<<<nodes4, 256, 0, stream>>>((const float4*)h3p, ald3, row_start, csr_src,
                                            b3, out, N);
}

// Round 4
// 382.449 us; speedup vs baseline: 1.5103x; 1.0830x over previous
//
#include <hip/hip_runtime.h>

// ---------------------------------------------------------------------------
// DoshaGAT: 3-layer GAT. R4:
//  - 8-deep edge software pipeline in both aggregates (latency-bound fix:
//    VALUBusy 54% / occ 70% / L3 path far below ceiling at R3).
//  - l3_prep fused into gat_aggregate<128> epilogue (o2 never materialized).
//  - x f32->bf16 conversion folded into gemm1 LDS staging.
// h layout: bf16, head-block-permuted (phys p = c16*CF+cf <-> logical
// L = cf*16+c16 within each head block); consumers re-index by the fixed perm.
// ---------------------------------------------------------------------------

#define WSZ 64

typedef short short8 __attribute__((ext_vector_type(8)));
typedef short short4v __attribute__((ext_vector_type(4)));
typedef float float4v __attribute__((ext_vector_type(4)));

__device__ inline unsigned short f2bf(float f) {  // RNE f32->bf16
  unsigned u = __float_as_uint(f);
  u += 0x7FFFu + ((u >> 16) & 1u);
  return (unsigned short)(u >> 16);
}
__device__ inline float bf2f(unsigned short u) {
  return __uint_as_float(((unsigned)u) << 16);
}

// ---------------- CSR build ----------------

__global__ __launch_bounds__(256) void hist_kernel(const int* __restrict__ dst, int E,
                                                   int* __restrict__ deg) {
  int e = blockIdx.x * 256 + threadIdx.x;
  if (e < E) atomicAdd(&deg[dst[e]], 1);
}

__global__ __launch_bounds__(256) void block_sums_kernel(const int* __restrict__ deg, int n,
                                                         int* __restrict__ bsum) {
  __shared__ int sh[256];
  int t = threadIdx.x;
  int base = blockIdx.x * 1024 + t * 4;
  int v = 0;
#pragma unroll
  for (int j = 0; j < 4; ++j) {
    int idx = base + j;
    if (idx < n) v += deg[idx];
  }
  sh[t] = v;
  __syncthreads();
  for (int off = 128; off >= 1; off >>= 1) {
    if (t < off) sh[t] += sh[t + off];
    __syncthreads();
  }
  if (t == 0) bsum[blockIdx.x] = sh[0];
}

__global__ void tiny_scan_kernel(int* bsum, int nb) {
  if (threadIdx.x == 0 && blockIdx.x == 0) {
    int run = 0;
    for (int i = 0; i < nb; ++i) {
      int v = bsum[i];
      bsum[i] = run;
      run += v;
    }
  }
}

__global__ __launch_bounds__(256) void scan_write_kernel(const int* __restrict__ deg, int n,
                                                         const int* __restrict__ bbase,
                                                         int* __restrict__ row_start,
                                                         int* __restrict__ cursor) {
  __shared__ int sh[256];
  int t = threadIdx.x;
  int base = blockIdx.x * 1024 + t * 4;
  int v[4];
  int s = 0;
#pragma unroll
  for (int j = 0; j < 4; ++j) {
    int idx = base + j;
    v[j] = (idx < n) ? deg[idx] : 0;
    s += v[j];
  }
  sh[t] = s;
  __syncthreads();
  for (int off = 1; off < 256; off <<= 1) {
    int x = (t >= off) ? sh[t - off] : 0;
    __syncthreads();
    sh[t] += x;
    __syncthreads();
  }
  int excl = sh[t] - s + bbase[blockIdx.x];
#pragma unroll
  for (int j = 0; j < 4; ++j) {
    int idx = base + j;
    if (idx < n) {
      row_start[idx] = excl;
      cursor[idx] = excl;
    }
    excl += v[j];
  }
  if (blockIdx.x == gridDim.x - 1 && t == 255) row_start[n] = excl;  // == E
}

__global__ __launch_bounds__(256) void scatter_kernel(const int* __restrict__ src,
                                                      const int* __restrict__ dst, int E,
                                                      int* __restrict__ cursor,
                                                      int* __restrict__ csr_src) {
  int e = blockIdx.x * 256 + threadIdx.x;
  if (e < E) {
    int d = dst[e];
    int p = atomicAdd(&cursor[d], 1);
    csr_src[p] = src[e];
  }
}

// ---------------- weight conversion ----------------

// W1 [128][256] -> W1t [256][128] bf16
__global__ __launch_bounds__(256) void conv_w1t_kernel(const float* __restrict__ W1,
                                                       unsigned short* __restrict__ W1t) {
  int idx = blockIdx.x * 256 + threadIdx.x;  // 32768
  int n = idx >> 7, k = idx & 127;
  W1t[idx] = f2bf(W1[k * 256 + n]);
}

// W2 [256][128] -> W2t [128][256] bf16, K rows permuted to layer-1 phys layout
__global__ __launch_bounds__(256) void conv_w2t_kernel(const float* __restrict__ W2,
                                                       unsigned short* __restrict__ W2t) {
  int idx = blockIdx.x * 256 + threadIdx.x;  // 32768
  int n = idx >> 8, p = idx & 255;
  int kl = (p & ~63) | ((p & 3) << 4) | ((p >> 2) & 15);
  W2t[idx] = f2bf(W2[kl * 128 + n]);
}

// ---------------- bf16 MFMA GEMM + fused attn-coeff epilogue ----------------
// C[M,BN] = A[M,K] @ B[K,BN]. 64-row blocks, 256 threads, 4 waves (wave=head).
// AF32: A is f32, converted to bf16 during LDS staging.

template <int K, int BN, bool AF32>
__global__ __launch_bounds__(256) void gemm_mfma(
    const void* __restrict__ Ap,            // [M][K] bf16 or f32
    const unsigned short* __restrict__ Bt,  // [BN][K] bf16 (pre-transposed)
    const float* __restrict__ a_s, const float* __restrict__ a_d,  // [BN] logical
    unsigned short* __restrict__ hout,      // [M][BN] bf16 physical layout
    float* __restrict__ als, float* __restrict__ ald,  // [M][4]
    int M) {
  constexpr int CF = BN / 64;  // col frags per wave
  constexpr int PAD = 36;
  __shared__ unsigned short As[64][PAD];
  __shared__ unsigned short Bs[BN][PAD];
  const int t = threadIdx.x;
  const int w = t >> 6;
  const int lane = t & 63;
  const int c16 = lane & 15;
  const int q = lane >> 4;
  const int bm = blockIdx.x * 64;
  const int arow = t >> 2;      // 0..63
  const int akc = (t & 3) * 8;  // 0,8,16,24

  float4v acc[4][CF];
#pragma unroll
  for (int rf = 0; rf < 4; ++rf)
#pragma unroll
    for (int cf = 0; cf < CF; ++cf) acc[rf][cf] = float4v{0.f, 0.f, 0.f, 0.f};

  for (int k0 = 0; k0 < K; k0 += 32) {
    {  // stage A tile 64x32 (8 elems/thread)
      int gr = bm + arow;
      if constexpr (AF32) {
        const float* Af = (const float*)Ap + (size_t)gr * K + k0 + akc;
        float4 v0 = make_float4(0.f, 0.f, 0.f, 0.f), v1 = v0;
        if (gr < M) {
          v0 = *(const float4*)Af;
          v1 = *(const float4*)(Af + 4);
        }
        ushort4 u0, u1;
        u0.x = f2bf(v0.x); u0.y = f2bf(v0.y); u0.z = f2bf(v0.z); u0.w = f2bf(v0.w);
        u1.x = f2bf(v1.x); u1.y = f2bf(v1.y); u1.z = f2bf(v1.z); u1.w = f2bf(v1.w);
        *(ushort4*)&As[arow][akc] = u0;
        *(ushort4*)&As[arow][akc + 4] = u1;
      } else {
        uint4 v = make_uint4(0u, 0u, 0u, 0u);
        if (gr < M) v = *(const uint4*)((const unsigned short*)Ap + (size_t)gr * K + k0 + akc);
        *(uint2*)&As[arow][akc] = make_uint2(v.x, v.y);
        *(uint2*)&As[arow][akc + 4] = make_uint2(v.z, v.w);
      }
    }
#pragma unroll
    for (int h = 0; h < BN / 64; ++h) {  // stage B tile BNx32
      int n = (t >> 2) + h * 64;
      uint4 v = *(const uint4*)(Bt + (size_t)n * K + k0 + akc);
      *(uint2*)&Bs[n][akc] = make_uint2(v.x, v.y);
      *(uint2*)&Bs[n][akc + 4] = make_uint2(v.z, v.w);
    }
    __syncthreads();
    short8 af[4], bfr[CF];
#pragma unroll
    for (int rf = 0; rf < 4; ++rf) {
      short4v lo = *(short4v*)&As[rf * 16 + c16][q * 8];
      short4v hi = *(short4v*)&As[rf * 16 + c16][q * 8 + 4];
      af[rf] = __builtin_shufflevector(lo, hi, 0, 1, 2, 3, 4, 5, 6, 7);
    }
#pragma unroll
    for (int cf = 0; cf < CF; ++cf) {
      int n = w * (CF * 16) + cf * 16 + c16;
      short4v lo = *(short4v*)&Bs[n][q * 8];
      short4v hi = *(short4v*)&Bs[n][q * 8 + 4];
      bfr[cf] = __builtin_shufflevector(lo, hi, 0, 1, 2, 3, 4, 5, 6, 7);
    }
#pragma unroll
    for (int rf = 0; rf < 4; ++rf)
#pragma unroll
      for (int cf = 0; cf < CF; ++cf)
        acc[rf][cf] =
            __builtin_amdgcn_mfma_f32_16x16x32_bf16(af[rf], bfr[cf], acc[rf][cf], 0, 0, 0);
    __syncthreads();
  }

  float sasv[CF], sadv[CF];
#pragma unroll
  for (int cf = 0; cf < CF; ++cf) {
    int L = w * (CF * 16) + cf * 16 + c16;
    sasv[cf] = a_s[L];
    sadv[cf] = a_d[L];
  }
#pragma unroll
  for (int rf = 0; rf < 4; ++rf) {
#pragma unroll
    for (int r = 0; r < 4; ++r) {
      int n = bm + rf * 16 + q * 4 + r;
      float ps = 0.f, pd = 0.f;
      unsigned short us[CF];
#pragma unroll
      for (int cf = 0; cf < CF; ++cf) {
        float v = acc[rf][cf][r];
        us[cf] = f2bf(v);
        ps += v * sasv[cf];
        pd += v * sadv[cf];
      }
#pragma unroll
      for (int off = 1; off <= 8; off <<= 1) {
        ps += __shfl_xor(ps, off, 16);
        pd += __shfl_xor(pd, off, 16);
      }
      if (n < M) {
        if constexpr (CF == 4) {
          ushort4 u;
          u.x = us[0]; u.y = us[1]; u.z = us[2]; u.w = us[3];
          *(ushort4*)(hout + (size_t)n * BN + w * 64 + c16 * 4) = u;
        } else {
          ushort2 u;
          u.x = us[0]; u.y = us[1];
          *(ushort2*)(hout + (size_t)n * BN + w * 32 + c16 * 2) = u;
        }
        if (c16 == 0) {
          als[(size_t)n * 4 + w] = ps;
          ald[(size_t)n * 4 + w] = pd;
        }
      }
    }
  }
}

// ---------------- GAT aggregation + bias + BN + ELU (+ fused layer-3 prep) --
// One wave per dst node; lane feature-parallel (phys cols); bf16 gather;
// 8-edge software pipeline; f32 accumulation.
// D=256: writes o1 as bf16 (next GEMM's A). D=128 + FUSEL3: computes
// h3 = o2@W3 and als3/ald3 in-register (o2 never materialized).

template <int D, bool FUSEL3>
__global__ __launch_bounds__(256) void gat_aggregate(
    const unsigned short* __restrict__ h_bf, const float* __restrict__ als,
    const float* __restrict__ ald, const int* __restrict__ row_start,
    const int* __restrict__ csr_src, const float* __restrict__ bias,
    const float* __restrict__ gamma, const float* __restrict__ beta,
    const float* __restrict__ bmean, const float* __restrict__ bvar,
    unsigned short* __restrict__ obf,  // D==256 output
    const float* __restrict__ W3, const float* __restrict__ a3s,
    const float* __restrict__ a3d, float4* __restrict__ h3p,
    float* __restrict__ ald3,  // FUSEL3 outputs
    int n_nodes) {
  constexpr int VPT = D / WSZ;
  constexpr int H = 4;
  __shared__ float w3s[384];
  __shared__ float sa3[6];
  if constexpr (FUSEL3) {
    for (int i = threadIdx.x; i < 384; i += 256) w3s[i] = W3[i];
    if (threadIdx.x < 3) {
      sa3[threadIdx.x] = a3s[threadIdx.x];
      sa3[3 + threadIdx.x] = a3d[threadIdx.x];
    }
    __syncthreads();
  }
  int wid = threadIdx.x >> 6, lane = threadIdx.x & 63;
  int n = blockIdx.x * 4 + wid;
  if (n >= n_nodes) return;  // N%4==0: never taken, kept for safety
  int c = lane * VPT;        // physical col base
  int hd = lane >> 4;        // head
  float aldv = ald[(size_t)n * H + hd];
  int row = row_start[n], end = row_start[n + 1];
  float acc[VPT] = {};
  float ssum = 0.f;
  int i = row;

#define EDGE_BLOCK(B)                                                          \
  for (; i + (B) - 1 < end; i += (B)) {                                        \
    int s[B];                                                                  \
    float e[B];                                                                \
    _Pragma("unroll") for (int j = 0; j < (B); ++j) s[j] = csr_src[i + j];     \
    _Pragma("unroll") for (int j = 0; j < (B); ++j) e[j] =                     \
        als[(size_t)s[j] * H + hd] + aldv;                                     \
    if constexpr (VPT == 4) {                                                  \
      ushort4 u[B];                                                            \
      _Pragma("unroll") for (int j = 0; j < (B); ++j) u[j] =                   \
          *(const ushort4*)(h_bf + (size_t)s[j] * D + c);                      \
      _Pragma("unroll") for (int j = 0; j < (B); ++j) {                        \
        float ee = e[j];                                                       \
        ee = (ee > 0.f) ? ee : 0.2f * ee;                                      \
        float ex = __expf(ee);                                                 \
        ssum += ex;                                                            \
        acc[0] += ex * bf2f(u[j].x);                                           \
        acc[1] += ex * bf2f(u[j].y);                                           \
        acc[2] += ex * bf2f(u[j].z);                                           \
        acc[3] += ex * bf2f(u[j].w);                                           \
      }                                                                        \
    } else {                                                                   \
      ushort2 u[B];                                                            \
      _Pragma("unroll") for (int j = 0; j < (B); ++j) u[j] =                   \
          *(const ushort2*)(h_bf + (size_t)s[j] * D + c);                      \
      _Pragma("unroll") for (int j = 0; j < (B); ++j) {                        \
        float ee = e[j];                                                       \
        ee = (ee > 0.f) ? ee : 0.2f * ee;                                      \
        float ex = __expf(ee);                                                 \
        ssum += ex;                                                            \
        acc[0] += ex * bf2f(u[j].x);                                           \
        acc[1] += ex * bf2f(u[j].y);                                           \
      }                                                                        \
    }                                                                          \
  }

  EDGE_BLOCK(8)
  EDGE_BLOCK(4)
  EDGE_BLOCK(1)
#undef EDGE_BLOCK

  float inv = 1.f / (ssum + 1e-16f);
#pragma unroll
  for (int j = 0; j < VPT; ++j) {
    int cl = hd * (VPT * 16) + j * 16 + (lane & 15);  // logical col
    float o = acc[j] * inv + bias[cl];
    o = (o - bmean[cl]) * rsqrtf(bvar[cl] + 1e-5f) * gamma[cl] + beta[cl];
    o = (o > 0.f) ? o : (__expf(o) - 1.f);  // ELU
    acc[j] = o;
  }
  if constexpr (!FUSEL3) {
    ushort4 u;
    u.x = f2bf(acc[0]); u.y = f2bf(acc[1]); u.z = f2bf(acc[2]); u.w = f2bf(acc[3]);
    *(ushort4*)(obf + (size_t)n * D + c) = u;
  } else {
    // fused l3_prep: o2 row lives in acc[0..1] (phys cols c, c+1).
    int k0l = hd * 32 + (lane & 15);  // logical k of acc[0]
    int k1l = k0l + 16;               // logical k of acc[1]
    float p0 = acc[0] * w3s[k0l * 3 + 0] + acc[1] * w3s[k1l * 3 + 0];
    float p1 = acc[0] * w3s[k0l * 3 + 1] + acc[1] * w3s[k1l * 3 + 1];
    float p2 = acc[0] * w3s[k0l * 3 + 2] + acc[1] * w3s[k1l * 3 + 2];
#pragma unroll
    for (int off = 32; off >= 1; off >>= 1) {
      p0 += __shfl_xor(p0, off, 64);
      p1 += __shfl_xor(p1, off, 64);
      p2 += __shfl_xor(p2, off, 64);
    }
    if (lane == 0) {
      float als3 = p0 * sa3[0] + p1 * sa3[1] + p2 * sa3[2];
      float ad3 = p0 * sa3[3] + p1 * sa3[4] + p2 * sa3[5];
      h3p[n] = make_float4(p0, p1, p2, als3);
      ald3[n] = ad3;
    }
  }
}

// ---------------- layer 3 aggregation + log_softmax -------------------------

__global__ __launch_bounds__(256) void l3_agg_kernel(const float4* __restrict__ h3p,
                                                     const float* __restrict__ ald3,
                                                     const int* __restrict__ row_start,
                                                     const int* __restrict__ csr_src,
                                                     const float* __restrict__ b3,
                                                     float* __restrict__ out, int n_nodes) {
  int wid = threadIdx.x >> 6, lane = threadIdx.x & 63;
  int n = blockIdx.x * 4 + wid;
  if (n >= n_nodes) return;
  float aldv = ald3[n];
  int row = row_start[n], end = row_start[n + 1];
  float a0 = 0.f, a1 = 0.f, a2 = 0.f, ss = 0.f;
  for (int i = row + lane; i < end; i += 64) {
    int s = csr_src[i];
    float4 hv = h3p[s];
    float e = hv.w + aldv;
    e = (e > 0.f) ? e : 0.2f * e;
    float ex = __expf(e);
    ss += ex;
    a0 += ex * hv.x;
    a1 += ex * hv.y;
    a2 += ex * hv.z;
  }
#pragma unroll
  for (int off = 32; off >= 1; off >>= 1) {
    a0 += __shfl_xor(a0, off, 64);
    a1 += __shfl_xor(a1, off, 64);
    a2 += __shfl_xor(a2, off, 64);
    ss += __shfl_xor(ss, off, 64);
  }
  if (lane == 0) {
    float inv = 1.f / (ss + 1e-16f);
    float o0 = a0 * inv + b3[0];
    float o1 = a1 * inv + b3[1];
    float o2 = a2 * inv + b3[2];
    float m = fmaxf(o0, fmaxf(o1, o2));
    float lse = m + logf(expf(o0 - m) + expf(o1 - m) + expf(o2 - m));
    out[n * 3 + 0] = o0 - lse;
    out[n * 3 + 1] = o1 - lse;
    out[n * 3 + 2] = o2 - lse;
  }
}

// ---------------------------------------------------------------------------

extern "C" void kernel_launch(void* const* d_in, const int* in_sizes, int n_in,
                              void* d_out, int out_size, void* d_ws, size_t ws_size,
                              hipStream_t stream) {
  const float* x   = (const float*)d_in[0];
  const int*   ei  = (const int*)d_in[1];
  const float* W1  = (const float*)d_in[2];
  const float* a1s = (const float*)d_in[3];
  const float* a1d = (const float*)d_in[4];
  const float* b1  = (const float*)d_in[5];
  const float* g1v = (const float*)d_in[6];
  const float* be1 = (const float*)d_in[7];
  const float* m1  = (const float*)d_in[8];
  const float* v1  = (const float*)d_in[9];
  const float* W2  = (const float*)d_in[10];
  const float* a2s = (const float*)d_in[11];
  const float* a2d = (const float*)d_in[12];
  const float* b2  = (const float*)d_in[13];
  const float* g2v = (const float*)d_in[14];
  const float* be2 = (const float*)d_in[15];
  const float* m2  = (const float*)d_in[16];
  const float* v2  = (const float*)d_in[17];
  const float* W3  = (const float*)d_in[18];
  const float* a3s = (const float*)d_in[19];
  const float* a3d = (const float*)d_in[20];
  const float* b3  = (const float*)d_in[21];
  float* out = (float*)d_out;

  const int N = in_sizes[0] / 128;  // 50000
  const int E = in_sizes[1] / 2;    // 850000
  const int* srcv = ei;
  const int* dstv = ei + E;

  // workspace carve-up (~75 MB)
  float* wsf  = (float*)d_ws;
  float* als1 = wsf;                  // N*4
  float* ald1 = als1 + (size_t)N * 4;
  float* als2 = ald1 + (size_t)N * 4;
  float* ald2 = als2 + (size_t)N * 4;
  float* h3p  = ald2 + (size_t)N * 4;  // N*4 (float4 rows)
  float* ald3 = h3p + (size_t)N * 4;   // N
  unsigned short* h_bf1 = (unsigned short*)(ald3 + N);  // N*256
  unsigned short* o1_bf = h_bf1 + (size_t)N * 256;      // N*256
  unsigned short* h_bf2 = o1_bf + (size_t)N * 256;      // N*128
  unsigned short* W1t   = h_bf2 + (size_t)N * 128;      // 256*128
  unsigned short* W2t   = W1t + 256 * 128;              // 128*256
  int* deg       = (int*)(W2t + 128 * 256);  // N
  int* row_start = deg + N;                  // N+1
  int* cursor    = row_start + (N + 1);      // N+1
  int* csr_src   = cursor + (N + 1);         // E
  int* bsum      = csr_src + E;              // 1024

  const int eb = (E + 255) / 256;
  const int nb = (N + 1023) / 1024;
  const int nodes4 = (N + 3) / 4;
  const int mblocks = (N + 63) / 64;

  // weight conversions
  conv_w1t_kernel<<<128, 256, 0, stream>>>(W1, W1t);
  conv_w2t_kernel<<<128, 256, 0, stream>>>(W2, W2t);

  // CSR build (shared by all 3 layers)
  hipMemsetAsync(deg, 0, (size_t)N * sizeof(int), stream);
  hist_kernel<<<eb, 256, 0, stream>>>(dstv, E, deg);
  block_sums_kernel<<<nb, 256, 0, stream>>>(deg, N, bsum);
  tiny_scan_kernel<<<1, 64, 0, stream>>>(bsum, nb);
  scan_write_kernel<<<nb, 256, 0, stream>>>(deg, N, bsum, row_start, cursor);
  scatter_kernel<<<eb, 256, 0, stream>>>(srcv, dstv, E, cursor, csr_src);

  // layer 1: h1 = x @ W1 (f32 A converted in staging), fused als1/ald1
  gemm_mfma<128, 256, true><<<mblocks, 256, 0, stream>>>(x, W1t, a1s, a1d, h_bf1, als1,
                                                         ald1, N);
  gat_aggregate<256, false><<<nodes4, 256, 0, stream>>>(
      h_bf1, als1, ald1, row_start, csr_src, b1, g1v, be1, m1, v1, o1_bf, nullptr, nullptr,
      nullptr, nullptr, nullptr, N);
  // layer 2
  gemm_mfma<256, 128, false><<<mblocks, 256, 0, stream>>>(o1_bf, W2t, a2s, a2d, h_bf2, als2,
                                                          ald2, N);
  gat_aggregate<128, true><<<nodes4, 256, 0, stream>>>(
      h_bf2, als2, ald2, row_start, csr_src, b2, g2v, be2, m2, v2, nullptr, W3, a3s, a3d,
      (float4*)h3p, ald3, N);
  // layer 3 + log_softmax
  l3_agg_kernel<<<nodes4, 256, 0, stream>>>((const float4*)h3p, ald3, row_start, csr_src,
                                            b3, out, N);
}